// Round 2
// baseline (1172.038 us; speedup 1.0000x reference)
//
#include <hip/hip_runtime.h>
#include <hip/hip_bf16.h>

#define D 64   // LATENT

// ---------------- degree ----------------

__global__ void k_deg(const int* __restrict__ to, int* __restrict__ deg, int E) {
    int i = blockIdx.x * blockDim.x + threadIdx.x;
    if (i < E) atomicAdd(&deg[to[i]], 1);
}

__global__ void k_dis(const int* __restrict__ deg, float* __restrict__ dis, int N) {
    int i = blockIdx.x * blockDim.x + threadIdx.x;
    if (i < N) {
        int d = deg[i];
        dis[i] = (d > 0) ? rsqrtf((float)d) : 0.0f;
    }
}

// ---------------- exclusive prefix scan over deg -> row_start ----------------

__global__ void k_scan1(const int* __restrict__ deg, int* __restrict__ row_start,
                        int* __restrict__ block_sums, int N) {
    __shared__ int s[256];
    int t = threadIdx.x;
    int i = blockIdx.x * 256 + t;
    int x = (i < N) ? deg[i] : 0;
    s[t] = x;
    __syncthreads();
    #pragma unroll
    for (int off = 1; off < 256; off <<= 1) {
        int v = s[t] + ((t >= off) ? s[t - off] : 0);
        __syncthreads();
        s[t] = v;
        __syncthreads();
    }
    if (i < N) row_start[i] = s[t] - x;          // exclusive within block
    if (t == 255) block_sums[blockIdx.x] = s[255];
}

__global__ void k_scan2(int* __restrict__ bs, int nb) {
    __shared__ int s[1024];
    int t = threadIdx.x;
    int x = (t < nb) ? bs[t] : 0;
    s[t] = x;
    __syncthreads();
    #pragma unroll
    for (int off = 1; off < 1024; off <<= 1) {
        int v = s[t] + ((t >= off) ? s[t - off] : 0);
        __syncthreads();
        s[t] = v;
        __syncthreads();
    }
    if (t < nb) bs[t] = s[t] - x;                // exclusive block offsets
}

__global__ void k_scan3(int* __restrict__ row_start, const int* __restrict__ bs,
                        int N, int E) {
    int i = blockIdx.x * 256 + threadIdx.x;
    if (i < N) row_start[i] += bs[i >> 8];
    if (i == 0) row_start[N] = E;
}

// ---------------- CSR fill (by target) ----------------

__global__ void k_fill(const int* __restrict__ frm, const int* __restrict__ to,
                       const int* __restrict__ row_start, int* __restrict__ cursor,
                       const float* __restrict__ dis,
                       int* __restrict__ csr_frm, float* __restrict__ csr_norm, int E) {
    int i = blockIdx.x * blockDim.x + threadIdx.x;
    if (i >= E) return;
    int t = to[i];
    int f = frm[i];
    int pos = row_start[t] + atomicAdd(&cursor[t], 1);
    csr_frm[pos] = f;
    csr_norm[pos] = dis[f] * dis[t];
}

// ---------------- emb0 = embedding + feature projection ----------------
// One wave (64 lanes) per node; lane = dim. Writes emb0 to out0 and
// initializes the layer-sum accumulator out1.

__global__ void k_emb0(const float* __restrict__ emb,
                       const float* __restrict__ uf,    // [NU,16]
                       const float* __restrict__ bn,    // [NB,8]
                       const float* __restrict__ bg,    // [NB,32]
                       const float* __restrict__ Wu,    // [16,64]
                       const float* __restrict__ bu,    // [64]
                       const float* __restrict__ Wn,    // [8,64]
                       const float* __restrict__ bnb,   // [64]
                       const float* __restrict__ Wg,    // [32,64]
                       const float* __restrict__ bgb,   // [64]
                       float* __restrict__ out0, float* __restrict__ acc,
                       int N, int NU) {
    int tid = threadIdx.x;
    int lane = tid & 63;
    int node = blockIdx.x * 4 + (tid >> 6);
    if (node >= N) return;

    float p;
    if (node < NU) {
        p = bu[lane];
        const float* f = uf + (size_t)node * 16;
        #pragma unroll
        for (int k = 0; k < 16; k++)
            p += f[k] * Wu[k * D + lane];
    } else {
        int b = node - NU;
        p = bnb[lane] + bgb[lane];
        const float* fn = bn + (size_t)b * 8;
        #pragma unroll
        for (int k = 0; k < 8; k++)
            p += fn[k] * Wn[k * D + lane];
        const float* fg = bg + (size_t)b * 32;
        #pragma unroll
        for (int k = 0; k < 32; k++)
            p += fg[k] * Wg[k * D + lane];
    }

    size_t idx = (size_t)node * D + lane;
    float v = emb[idx] + p;
    out0[idx] = v;
    acc[idx]  = v;
}

// ---------------- one propagation layer (atomic-free per-node gather) ----------------

__global__ void k_prop(const int* __restrict__ row_start,
                       const int* __restrict__ csr_frm,
                       const float* __restrict__ csr_norm,
                       const float* __restrict__ emb_in,
                       float* __restrict__ emb_out,
                       float* __restrict__ acc, int N) {
    int tid = threadIdx.x;
    int lane = tid & 63;
    int node = blockIdx.x * 4 + (tid >> 6);
    if (node >= N) return;

    int s = row_start[node];
    int e = row_start[node + 1];
    float a = 0.0f;
    for (int i = s; i < e; i++) {
        int   j = csr_frm[i];
        float w = csr_norm[i];
        a += w * emb_in[(size_t)j * D + lane];
    }
    size_t idx = (size_t)node * D + lane;
    emb_out[idx] = a;
    acc[idx]    += a;
}

// ---------------- finalize: out1 = acc / 4 (in place) ----------------

__global__ void k_final(float* __restrict__ acc, int n) {
    int i = blockIdx.x * blockDim.x + threadIdx.x;
    if (i < n) acc[i] *= 0.25f;
}

// ---------------- launch ----------------

extern "C" void kernel_launch(void* const* d_in, const int* in_sizes, int n_in,
                              void* d_out, int out_size, void* d_ws, size_t ws_size,
                              hipStream_t stream) {
    const int E  = in_sizes[0] / 2;
    const int N  = in_sizes[1] / D;
    const int NU = in_sizes[2] / 16;

    const int*   frm = (const int*)d_in[0];
    const int*   to  = frm + E;
    const float* emb = (const float*)d_in[1];
    const float* uf  = (const float*)d_in[2];
    const float* bn  = (const float*)d_in[3];
    const float* bg  = (const float*)d_in[4];
    const float* Wu  = (const float*)d_in[5];
    const float* bu  = (const float*)d_in[6];
    const float* Wn  = (const float*)d_in[7];
    const float* bnb = (const float*)d_in[8];
    const float* Wg  = (const float*)d_in[9];
    const float* bgb = (const float*)d_in[10];

    // workspace layout
    char* p = (char*)d_ws;
    const size_t ND = (size_t)N * D;
    float* emb_a     = (float*)p;  p += ND * sizeof(float);
    float* emb_b     = (float*)p;  p += ND * sizeof(float);
    float* dis       = (float*)p;  p += (size_t)N * sizeof(float);
    int*   deg       = (int*)p;    p += (size_t)N * sizeof(int);
    int*   cursor    = (int*)p;    p += (size_t)N * sizeof(int);
    int*   row_start = (int*)p;    p += ((size_t)N + 16) * sizeof(int);
    int*   block_sums= (int*)p;    p += 1024 * sizeof(int);
    int*   csr_frm   = (int*)p;    p += (size_t)E * sizeof(int);
    float* csr_norm  = (float*)p;  p += (size_t)E * sizeof(float);

    hipMemsetAsync(deg,    0, (size_t)N * sizeof(int), stream);
    hipMemsetAsync(cursor, 0, (size_t)N * sizeof(int), stream);

    const int TB = 256;
    const int gridE = (E + TB - 1) / TB;
    const int gridN = (N + TB - 1) / TB;
    const int nb    = gridN;                 // scan blocks (must be <= 1024)
    const int gridNode = (N + 3) / 4;        // 4 nodes (waves) per 256-thread block
    const int gridND   = (int)((ND + TB - 1) / TB);

    k_deg  <<<gridE, TB, 0, stream>>>(to, deg, E);
    k_dis  <<<gridN, TB, 0, stream>>>(deg, dis, N);
    k_scan1<<<nb,    TB, 0, stream>>>(deg, row_start, block_sums, N);
    k_scan2<<<1,   1024, 0, stream>>>(block_sums, nb);
    k_scan3<<<gridN, TB, 0, stream>>>(row_start, block_sums, N, E);
    k_fill <<<gridE, TB, 0, stream>>>(frm, to, row_start, cursor, dis, csr_frm, csr_norm, E);

    float* out0 = (float*)d_out;       // emb0 output
    float* acc  = out0 + ND;           // layer-mean output (accumulated in place, fp32)

    k_emb0<<<gridNode, TB, 0, stream>>>(emb, uf, bn, bg, Wu, bu, Wn, bnb, Wg, bgb,
                                        out0, acc, N, NU);

    k_prop<<<gridNode, TB, 0, stream>>>(row_start, csr_frm, csr_norm, out0,  emb_a, acc, N);
    k_prop<<<gridNode, TB, 0, stream>>>(row_start, csr_frm, csr_norm, emb_a, emb_b, acc, N);
    k_prop<<<gridNode, TB, 0, stream>>>(row_start, csr_frm, csr_norm, emb_b, emb_a, acc, N);

    k_final<<<gridND, TB, 0, stream>>>(acc, (int)ND);
}

// Round 3
// 802.098 us; speedup vs baseline: 1.4612x; 1.4612x over previous
//
#include <hip/hip_runtime.h>

#define D 64   // LATENT

// ---------------- degree ----------------

__global__ void k_deg(const int* __restrict__ to, int* __restrict__ deg, int E) {
    int i = blockIdx.x * blockDim.x + threadIdx.x;
    if (i < E) atomicAdd(&deg[to[i]], 1);
}

// ---------------- scan1: block-local exclusive scan + dis = deg^-1/2 ----------------

__global__ void k_scan1(const int* __restrict__ deg, float* __restrict__ dis,
                        int* __restrict__ row_start, int* __restrict__ block_sums, int N) {
    __shared__ int s[256];
    int t = threadIdx.x;
    int i = blockIdx.x * 256 + t;
    int x = (i < N) ? deg[i] : 0;
    if (i < N) dis[i] = (x > 0) ? rsqrtf((float)x) : 0.0f;
    s[t] = x;
    __syncthreads();
    #pragma unroll
    for (int off = 1; off < 256; off <<= 1) {
        int v = s[t] + ((t >= off) ? s[t - off] : 0);
        __syncthreads();
        s[t] = v;
        __syncthreads();
    }
    if (i < N) row_start[i] = s[t] - x;          // exclusive within block
    if (t == 255) block_sums[blockIdx.x] = s[255];
}

__global__ void k_scan2(int* __restrict__ bs, int nb) {
    __shared__ int s[1024];
    int t = threadIdx.x;
    int x = (t < nb) ? bs[t] : 0;
    s[t] = x;
    __syncthreads();
    #pragma unroll
    for (int off = 1; off < 1024; off <<= 1) {
        int v = s[t] + ((t >= off) ? s[t - off] : 0);
        __syncthreads();
        s[t] = v;
        __syncthreads();
    }
    if (t < nb) bs[t] = s[t] - x;                // exclusive block offsets
}

__global__ void k_scan3(int* __restrict__ row_start, const int* __restrict__ bs, int N) {
    int i = blockIdx.x * 256 + threadIdx.x;
    if (i < N) row_start[i] += bs[i >> 8];
}

// ---------------- CSR fill (by target); row_start mutates into row_end ----------------

__global__ void k_fill(const int* __restrict__ frm, const int* __restrict__ to,
                       int* __restrict__ row_pos, const float* __restrict__ dis,
                       int* __restrict__ csr_frm, float* __restrict__ csr_norm, int E) {
    int i = blockIdx.x * blockDim.x + threadIdx.x;
    if (i >= E) return;
    int t = to[i];
    int f = frm[i];
    int pos = atomicAdd(&row_pos[t], 1);         // row_start -> row_end as it fills
    csr_frm[pos] = f;
    csr_norm[pos] = dis[f] * dis[t];
}

// ---------------- emb0 = embedding + feature projection ----------------
// One wave per node; lane = dim. Writes emb0 to out0 and seeds acc.

__global__ void k_emb0(const float* __restrict__ emb,
                       const float* __restrict__ uf,    // [NU,16]
                       const float* __restrict__ bn,    // [NB,8]
                       const float* __restrict__ bg,    // [NB,32]
                       const float* __restrict__ Wu,    // [16,64]
                       const float* __restrict__ bu,    // [64]
                       const float* __restrict__ Wn,    // [8,64]
                       const float* __restrict__ bnb,   // [64]
                       const float* __restrict__ Wg,    // [32,64]
                       const float* __restrict__ bgb,   // [64]
                       float* __restrict__ out0, float* __restrict__ acc,
                       int N, int NU) {
    int tid = threadIdx.x;
    int lane = tid & 63;
    int node = blockIdx.x * 4 + (tid >> 6);
    if (node >= N) return;

    float p;
    if (node < NU) {
        p = bu[lane];
        const float* f = uf + (size_t)node * 16;
        #pragma unroll
        for (int k = 0; k < 16; k++)
            p += f[k] * Wu[k * D + lane];
    } else {
        int b = node - NU;
        p = bnb[lane] + bgb[lane];
        const float* fn = bn + (size_t)b * 8;
        #pragma unroll
        for (int k = 0; k < 8; k++)
            p += fn[k] * Wn[k * D + lane];
        const float* fg = bg + (size_t)b * 32;
        #pragma unroll
        for (int k = 0; k < 32; k++)
            p += fg[k] * Wg[k * D + lane];
    }

    size_t idx = (size_t)node * D + lane;
    float v = emb[idx] + p;
    out0[idx] = v;
    acc[idx]  = v;
}

// ---------------- propagation layer, unroll-8 for memory-level parallelism ----------------
// row_end[n] = end offset of row n; start = row_end[n-1] (0 for n=0).

__global__ void k_prop(const int* __restrict__ row_end,
                       const int* __restrict__ csr_frm,
                       const float* __restrict__ csr_norm,
                       const float* __restrict__ emb_in,
                       float* __restrict__ emb_out,
                       float* __restrict__ acc, int N) {
    int lane = threadIdx.x & 63;
    int node = blockIdx.x * 4 + (threadIdx.x >> 6);
    if (node >= N) return;

    int s = (node > 0) ? row_end[node - 1] : 0;
    int e = row_end[node];

    float a0 = 0, a1 = 0, a2 = 0, a3 = 0, a4 = 0, a5 = 0, a6 = 0, a7 = 0;
    int i = s;
    for (; i + 8 <= e; i += 8) {
        int j0 = csr_frm[i+0], j1 = csr_frm[i+1], j2 = csr_frm[i+2], j3 = csr_frm[i+3];
        int j4 = csr_frm[i+4], j5 = csr_frm[i+5], j6 = csr_frm[i+6], j7 = csr_frm[i+7];
        float w0 = csr_norm[i+0], w1 = csr_norm[i+1], w2 = csr_norm[i+2], w3 = csr_norm[i+3];
        float w4 = csr_norm[i+4], w5 = csr_norm[i+5], w6 = csr_norm[i+6], w7 = csr_norm[i+7];
        float v0 = emb_in[(size_t)j0 * D + lane];
        float v1 = emb_in[(size_t)j1 * D + lane];
        float v2 = emb_in[(size_t)j2 * D + lane];
        float v3 = emb_in[(size_t)j3 * D + lane];
        float v4 = emb_in[(size_t)j4 * D + lane];
        float v5 = emb_in[(size_t)j5 * D + lane];
        float v6 = emb_in[(size_t)j6 * D + lane];
        float v7 = emb_in[(size_t)j7 * D + lane];
        a0 += w0 * v0; a1 += w1 * v1; a2 += w2 * v2; a3 += w3 * v3;
        a4 += w4 * v4; a5 += w5 * v5; a6 += w6 * v6; a7 += w7 * v7;
    }
    for (; i < e; i++)
        a0 += csr_norm[i] * emb_in[(size_t)csr_frm[i] * D + lane];

    float a = ((a0 + a1) + (a2 + a3)) + ((a4 + a5) + (a6 + a7));
    size_t idx = (size_t)node * D + lane;
    emb_out[idx] = a;
    acc[idx]    += a;
}

// ---------------- last layer fused: out = (acc + gather) / 4, no emb_out ----------------

__global__ void k_prop_last(const int* __restrict__ row_end,
                            const int* __restrict__ csr_frm,
                            const float* __restrict__ csr_norm,
                            const float* __restrict__ emb_in,
                            float* __restrict__ acc, int N) {
    int lane = threadIdx.x & 63;
    int node = blockIdx.x * 4 + (threadIdx.x >> 6);
    if (node >= N) return;

    int s = (node > 0) ? row_end[node - 1] : 0;
    int e = row_end[node];

    float a0 = 0, a1 = 0, a2 = 0, a3 = 0, a4 = 0, a5 = 0, a6 = 0, a7 = 0;
    int i = s;
    for (; i + 8 <= e; i += 8) {
        int j0 = csr_frm[i+0], j1 = csr_frm[i+1], j2 = csr_frm[i+2], j3 = csr_frm[i+3];
        int j4 = csr_frm[i+4], j5 = csr_frm[i+5], j6 = csr_frm[i+6], j7 = csr_frm[i+7];
        float w0 = csr_norm[i+0], w1 = csr_norm[i+1], w2 = csr_norm[i+2], w3 = csr_norm[i+3];
        float w4 = csr_norm[i+4], w5 = csr_norm[i+5], w6 = csr_norm[i+6], w7 = csr_norm[i+7];
        float v0 = emb_in[(size_t)j0 * D + lane];
        float v1 = emb_in[(size_t)j1 * D + lane];
        float v2 = emb_in[(size_t)j2 * D + lane];
        float v3 = emb_in[(size_t)j3 * D + lane];
        float v4 = emb_in[(size_t)j4 * D + lane];
        float v5 = emb_in[(size_t)j5 * D + lane];
        float v6 = emb_in[(size_t)j6 * D + lane];
        float v7 = emb_in[(size_t)j7 * D + lane];
        a0 += w0 * v0; a1 += w1 * v1; a2 += w2 * v2; a3 += w3 * v3;
        a4 += w4 * v4; a5 += w5 * v5; a6 += w6 * v6; a7 += w7 * v7;
    }
    for (; i < e; i++)
        a0 += csr_norm[i] * emb_in[(size_t)csr_frm[i] * D + lane];

    float a = ((a0 + a1) + (a2 + a3)) + ((a4 + a5) + (a6 + a7));
    size_t idx = (size_t)node * D + lane;
    acc[idx] = (acc[idx] + a) * 0.25f;
}

// ---------------- launch ----------------

extern "C" void kernel_launch(void* const* d_in, const int* in_sizes, int n_in,
                              void* d_out, int out_size, void* d_ws, size_t ws_size,
                              hipStream_t stream) {
    const int E  = in_sizes[0] / 2;
    const int N  = in_sizes[1] / D;
    const int NU = in_sizes[2] / 16;

    const int*   frm = (const int*)d_in[0];
    const int*   to  = frm + E;
    const float* emb = (const float*)d_in[1];
    const float* uf  = (const float*)d_in[2];
    const float* bn  = (const float*)d_in[3];
    const float* bg  = (const float*)d_in[4];
    const float* Wu  = (const float*)d_in[5];
    const float* bu  = (const float*)d_in[6];
    const float* Wn  = (const float*)d_in[7];
    const float* bnb = (const float*)d_in[8];
    const float* Wg  = (const float*)d_in[9];
    const float* bgb = (const float*)d_in[10];

    // workspace layout
    char* p = (char*)d_ws;
    const size_t ND = (size_t)N * D;
    float* emb_a     = (float*)p;  p += ND * sizeof(float);
    float* emb_b     = (float*)p;  p += ND * sizeof(float);
    float* dis       = (float*)p;  p += (size_t)N * sizeof(float);
    int*   deg       = (int*)p;    p += (size_t)N * sizeof(int);
    int*   row_start = (int*)p;    p += ((size_t)N + 16) * sizeof(int);
    int*   block_sums= (int*)p;    p += 1024 * sizeof(int);
    int*   csr_frm   = (int*)p;    p += (size_t)E * sizeof(int);
    float* csr_norm  = (float*)p;  p += (size_t)E * sizeof(float);

    hipMemsetAsync(deg, 0, (size_t)N * sizeof(int), stream);

    const int TB = 256;
    const int gridE = (E + TB - 1) / TB;
    const int gridN = (N + TB - 1) / TB;
    const int nb    = gridN;                 // scan blocks (must be <= 1024)
    const int gridNode = (N + 3) / 4;        // 4 nodes (waves) per 256-thread block

    k_deg  <<<gridE, TB, 0, stream>>>(to, deg, E);
    k_scan1<<<nb,    TB, 0, stream>>>(deg, dis, row_start, block_sums, N);
    k_scan2<<<1,   1024, 0, stream>>>(block_sums, nb);
    k_scan3<<<gridN, TB, 0, stream>>>(row_start, block_sums, N);
    k_fill <<<gridE, TB, 0, stream>>>(frm, to, row_start, dis, csr_frm, csr_norm, E);

    float* out0 = (float*)d_out;       // emb0 output
    float* acc  = out0 + ND;           // layer-mean output (accumulated in place, fp32)

    k_emb0<<<gridNode, TB, 0, stream>>>(emb, uf, bn, bg, Wu, bu, Wn, bnb, Wg, bgb,
                                        out0, acc, N, NU);

    // row_start now holds row-END offsets (mutated by k_fill)
    k_prop     <<<gridNode, TB, 0, stream>>>(row_start, csr_frm, csr_norm, out0,  emb_a, acc, N);
    k_prop     <<<gridNode, TB, 0, stream>>>(row_start, csr_frm, csr_norm, emb_a, emb_b, acc, N);
    k_prop_last<<<gridNode, TB, 0, stream>>>(row_start, csr_frm, csr_norm, emb_b, acc, N);
}

// Round 4
// 740.331 us; speedup vs baseline: 1.5831x; 1.0834x over previous
//
#include <hip/hip_runtime.h>
#include <hip/hip_bf16.h>

typedef __hip_bfloat16 bf16;

#define D 64   // LATENT

// ---------------- degree ----------------

__global__ void k_deg(const int* __restrict__ to, int* __restrict__ deg, int E) {
    int i = blockIdx.x * blockDim.x + threadIdx.x;
    if (i < E) atomicAdd(&deg[to[i]], 1);
}

// ---------------- scan1: block-local exclusive scan + dis = deg^-1/2 ----------------

__global__ void k_scan1(const int* __restrict__ deg, float* __restrict__ dis,
                        int* __restrict__ row_start, int* __restrict__ block_sums, int N) {
    __shared__ int s[256];
    int t = threadIdx.x;
    int i = blockIdx.x * 256 + t;
    int x = (i < N) ? deg[i] : 0;
    if (i < N) dis[i] = (x > 0) ? rsqrtf((float)x) : 0.0f;
    s[t] = x;
    __syncthreads();
    #pragma unroll
    for (int off = 1; off < 256; off <<= 1) {
        int v = s[t] + ((t >= off) ? s[t - off] : 0);
        __syncthreads();
        s[t] = v;
        __syncthreads();
    }
    if (i < N) row_start[i] = s[t] - x;          // exclusive within block
    if (t == 255) block_sums[blockIdx.x] = s[255];
}

__global__ void k_scan2(int* __restrict__ bs, int nb) {
    __shared__ int s[1024];
    int t = threadIdx.x;
    int x = (t < nb) ? bs[t] : 0;
    s[t] = x;
    __syncthreads();
    #pragma unroll
    for (int off = 1; off < 1024; off <<= 1) {
        int v = s[t] + ((t >= off) ? s[t - off] : 0);
        __syncthreads();
        s[t] = v;
        __syncthreads();
    }
    if (t < nb) bs[t] = s[t] - x;                // exclusive block offsets
}

__global__ void k_scan3(int* __restrict__ row_start, const int* __restrict__ bs, int N) {
    int i = blockIdx.x * 256 + threadIdx.x;
    if (i < N) row_start[i] += bs[i >> 8];
}

// ---------------- CSR fill; single 8B packed scatter per edge ----------------
// row_start mutates into row_end as it fills.

__global__ void k_fill(const int* __restrict__ frm, const int* __restrict__ to,
                       int* __restrict__ row_pos, const float* __restrict__ dis,
                       int2* __restrict__ csr, int E) {
    int i = blockIdx.x * blockDim.x + threadIdx.x;
    if (i >= E) return;
    int t = to[i];
    int f = frm[i];
    int pos = atomicAdd(&row_pos[t], 1);
    int2 pk;
    pk.x = f;
    pk.y = __float_as_int(dis[f] * dis[t]);
    csr[pos] = pk;
}

// ---------------- emb0 = embedding + feature projection ----------------
// One wave per node; lane = dim. Writes fp32 emb0 to out0 and bf16 copy for prop.

__global__ void k_emb0(const float* __restrict__ emb,
                       const float* __restrict__ uf,    // [NU,16]
                       const float* __restrict__ bn,    // [NB,8]
                       const float* __restrict__ bg,    // [NB,32]
                       const float* __restrict__ Wu,    // [16,64]
                       const float* __restrict__ bu,    // [64]
                       const float* __restrict__ Wn,    // [8,64]
                       const float* __restrict__ bnb,   // [64]
                       const float* __restrict__ Wg,    // [32,64]
                       const float* __restrict__ bgb,   // [64]
                       float* __restrict__ out0, bf16* __restrict__ e0_bf,
                       int N, int NU) {
    int tid = threadIdx.x;
    int lane = tid & 63;
    int node = blockIdx.x * 4 + (tid >> 6);
    if (node >= N) return;

    float p;
    if (node < NU) {
        p = bu[lane];
        const float* f = uf + (size_t)node * 16;
        #pragma unroll
        for (int k = 0; k < 16; k++)
            p += f[k] * Wu[k * D + lane];
    } else {
        int b = node - NU;
        p = bnb[lane] + bgb[lane];
        const float* fn = bn + (size_t)b * 8;
        #pragma unroll
        for (int k = 0; k < 8; k++)
            p += fn[k] * Wn[k * D + lane];
        const float* fg = bg + (size_t)b * 32;
        #pragma unroll
        for (int k = 0; k < 32; k++)
            p += fg[k] * Wg[k * D + lane];
    }

    size_t idx = (size_t)node * D + lane;
    float v = emb[idx] + p;
    out0[idx]  = v;
    e0_bf[idx] = __float2bfloat16(v);
}

// ---------------- propagation layer: bf16 gather, fp32 accumulate, bf16 out ----------------
// row_end[n] = end offset of row n; start = row_end[n-1] (0 for n=0).

__global__ void k_prop(const int* __restrict__ row_end,
                       const int2* __restrict__ csr,
                       const bf16* __restrict__ emb_in,
                       bf16* __restrict__ emb_out, int N) {
    int lane = threadIdx.x & 63;
    int node = blockIdx.x * 4 + (threadIdx.x >> 6);
    if (node >= N) return;

    int s = (node > 0) ? row_end[node - 1] : 0;
    int e = row_end[node];

    float a0 = 0, a1 = 0, a2 = 0, a3 = 0, a4 = 0, a5 = 0, a6 = 0, a7 = 0;
    int i = s;
    for (; i + 8 <= e; i += 8) {
        int2 p0 = csr[i+0], p1 = csr[i+1], p2 = csr[i+2], p3 = csr[i+3];
        int2 p4 = csr[i+4], p5 = csr[i+5], p6 = csr[i+6], p7 = csr[i+7];
        float v0 = __bfloat162float(emb_in[(size_t)p0.x * D + lane]);
        float v1 = __bfloat162float(emb_in[(size_t)p1.x * D + lane]);
        float v2 = __bfloat162float(emb_in[(size_t)p2.x * D + lane]);
        float v3 = __bfloat162float(emb_in[(size_t)p3.x * D + lane]);
        float v4 = __bfloat162float(emb_in[(size_t)p4.x * D + lane]);
        float v5 = __bfloat162float(emb_in[(size_t)p5.x * D + lane]);
        float v6 = __bfloat162float(emb_in[(size_t)p6.x * D + lane]);
        float v7 = __bfloat162float(emb_in[(size_t)p7.x * D + lane]);
        a0 += __int_as_float(p0.y) * v0; a1 += __int_as_float(p1.y) * v1;
        a2 += __int_as_float(p2.y) * v2; a3 += __int_as_float(p3.y) * v3;
        a4 += __int_as_float(p4.y) * v4; a5 += __int_as_float(p5.y) * v5;
        a6 += __int_as_float(p6.y) * v6; a7 += __int_as_float(p7.y) * v7;
    }
    for (; i < e; i++) {
        int2 pk = csr[i];
        a0 += __int_as_float(pk.y) * __bfloat162float(emb_in[(size_t)pk.x * D + lane]);
    }

    float a = ((a0 + a1) + (a2 + a3)) + ((a4 + a5) + (a6 + a7));
    emb_out[(size_t)node * D + lane] = __float2bfloat16(a);
}

// ---------------- finalize: out1 = (emb0 + l1 + l2 + l3) / 4 ----------------

__global__ void k_final(const float* __restrict__ out0,
                        const bf16* __restrict__ l1,
                        const bf16* __restrict__ l2,
                        const bf16* __restrict__ l3,
                        float* __restrict__ out1, size_t n) {
    size_t i = (size_t)blockIdx.x * blockDim.x + threadIdx.x;
    if (i < n)
        out1[i] = (out0[i] + __bfloat162float(l1[i]) + __bfloat162float(l2[i])
                   + __bfloat162float(l3[i])) * 0.25f;
}

// ---------------- launch ----------------

extern "C" void kernel_launch(void* const* d_in, const int* in_sizes, int n_in,
                              void* d_out, int out_size, void* d_ws, size_t ws_size,
                              hipStream_t stream) {
    const int E  = in_sizes[0] / 2;
    const int N  = in_sizes[1] / D;
    const int NU = in_sizes[2] / 16;

    const int*   frm = (const int*)d_in[0];
    const int*   to  = frm + E;
    const float* emb = (const float*)d_in[1];
    const float* uf  = (const float*)d_in[2];
    const float* bn  = (const float*)d_in[3];
    const float* bg  = (const float*)d_in[4];
    const float* Wu  = (const float*)d_in[5];
    const float* bu  = (const float*)d_in[6];
    const float* Wn  = (const float*)d_in[7];
    const float* bnb = (const float*)d_in[8];
    const float* Wg  = (const float*)d_in[9];
    const float* bgb = (const float*)d_in[10];

    // workspace layout
    char* p = (char*)d_ws;
    const size_t ND = (size_t)N * D;
    bf16*  e0_bf     = (bf16*)p;   p += ND * sizeof(bf16);
    bf16*  l1_bf     = (bf16*)p;   p += ND * sizeof(bf16);
    bf16*  l2_bf     = (bf16*)p;   p += ND * sizeof(bf16);
    bf16*  l3_bf     = (bf16*)p;   p += ND * sizeof(bf16);
    float* dis       = (float*)p;  p += (size_t)N * sizeof(float);
    int*   deg       = (int*)p;    p += (size_t)N * sizeof(int);
    int*   row_start = (int*)p;    p += ((size_t)N + 16) * sizeof(int);
    int*   block_sums= (int*)p;    p += 1024 * sizeof(int);
    int2*  csr       = (int2*)p;   p += (size_t)E * sizeof(int2);

    hipMemsetAsync(deg, 0, (size_t)N * sizeof(int), stream);

    const int TB = 256;
    const int gridE = (E + TB - 1) / TB;
    const int gridN = (N + TB - 1) / TB;
    const int nb    = gridN;                 // scan blocks (must be <= 1024)
    const int gridNode = (N + 3) / 4;        // 4 nodes (waves) per 256-thread block
    const int gridND   = (int)((ND + TB - 1) / TB);

    k_deg  <<<gridE, TB, 0, stream>>>(to, deg, E);
    k_scan1<<<nb,    TB, 0, stream>>>(deg, dis, row_start, block_sums, N);
    k_scan2<<<1,   1024, 0, stream>>>(block_sums, nb);
    k_scan3<<<gridN, TB, 0, stream>>>(row_start, block_sums, N);
    k_fill <<<gridE, TB, 0, stream>>>(frm, to, row_start, dis, csr, E);

    float* out0 = (float*)d_out;       // emb0 output (fp32)
    float* out1 = out0 + ND;           // layer-mean output (fp32)

    k_emb0<<<gridNode, TB, 0, stream>>>(emb, uf, bn, bg, Wu, bu, Wn, bnb, Wg, bgb,
                                        out0, e0_bf, N, NU);

    // row_start now holds row-END offsets (mutated by k_fill)
    k_prop<<<gridNode, TB, 0, stream>>>(row_start, csr, e0_bf, l1_bf, N);
    k_prop<<<gridNode, TB, 0, stream>>>(row_start, csr, l1_bf, l2_bf, N);
    k_prop<<<gridNode, TB, 0, stream>>>(row_start, csr, l2_bf, l3_bf, N);

    k_final<<<gridND, TB, 0, stream>>>(out0, l1_bf, l2_bf, l3_bf, out1, ND);
}

// Round 5
// 662.708 us; speedup vs baseline: 1.7686x; 1.1171x over previous
//
#include <hip/hip_runtime.h>
#include <hip/hip_bf16.h>

typedef __hip_bfloat16 bf16;

#define D 64   // LATENT

// ---------------- degree (4 independent atomic chains per thread) ----------------

__global__ __launch_bounds__(256) void k_deg(const int* __restrict__ to,
                                             int* __restrict__ deg, int E) {
    int t0 = blockIdx.x * blockDim.x + threadIdx.x;
    int stride = gridDim.x * blockDim.x;
    #pragma unroll
    for (int u = 0; u < 4; u++) {
        int i = t0 + u * stride;
        if (i < E) atomicAdd(&deg[to[i]], 1);
    }
}

// ---------------- scan1: block-local exclusive scan + dis = deg^-1/2 ----------------

__global__ void k_scan1(const int* __restrict__ deg, float* __restrict__ dis,
                        int* __restrict__ row_start, int* __restrict__ block_sums, int N) {
    __shared__ int s[256];
    int t = threadIdx.x;
    int i = blockIdx.x * 256 + t;
    int x = (i < N) ? deg[i] : 0;
    if (i < N) dis[i] = (x > 0) ? rsqrtf((float)x) : 0.0f;
    s[t] = x;
    __syncthreads();
    #pragma unroll
    for (int off = 1; off < 256; off <<= 1) {
        int v = s[t] + ((t >= off) ? s[t - off] : 0);
        __syncthreads();
        s[t] = v;
        __syncthreads();
    }
    if (i < N) row_start[i] = s[t] - x;          // exclusive within block
    if (t == 255) block_sums[blockIdx.x] = s[255];
}

__global__ void k_scan2(int* __restrict__ bs, int nb) {
    __shared__ int s[1024];
    int t = threadIdx.x;
    int x = (t < nb) ? bs[t] : 0;
    s[t] = x;
    __syncthreads();
    #pragma unroll
    for (int off = 1; off < 1024; off <<= 1) {
        int v = s[t] + ((t >= off) ? s[t - off] : 0);
        __syncthreads();
        s[t] = v;
        __syncthreads();
    }
    if (t < nb) bs[t] = s[t] - x;                // exclusive block offsets
}

__global__ void k_scan3(int* __restrict__ row_start, const int* __restrict__ bs, int N) {
    int i = blockIdx.x * 256 + threadIdx.x;
    if (i < N) row_start[i] += bs[i >> 8];
}

// ---------------- CSR fill; 4B scatter, 4 independent atomic chains ----------------
// row_start mutates into row_end as it fills.

__global__ __launch_bounds__(256) void k_fill(const int* __restrict__ frm,
                                              const int* __restrict__ to,
                                              int* __restrict__ row_pos,
                                              int* __restrict__ csr, int E) {
    int t0 = blockIdx.x * blockDim.x + threadIdx.x;
    int stride = gridDim.x * blockDim.x;
    int  ff[4], tt[4], pos[4];
    bool va[4];
    #pragma unroll
    for (int u = 0; u < 4; u++) {
        int i = t0 + u * stride;
        va[u] = (i < E);
        int ic = va[u] ? i : 0;
        tt[u] = to[ic];
        ff[u] = frm[ic];
    }
    #pragma unroll
    for (int u = 0; u < 4; u++)
        if (va[u]) pos[u] = atomicAdd(&row_pos[tt[u]], 1);
    #pragma unroll
    for (int u = 0; u < 4; u++)
        if (va[u]) csr[pos[u]] = ff[u];
}

// ---------------- emb0 = embedding + feature projection ----------------
// One wave per node; lane = dim. out0 = fp32 emb0; y0 = bf16(dis * emb0) gather table.

__global__ __launch_bounds__(256) void k_emb0(const float* __restrict__ emb,
                       const float* __restrict__ uf,    // [NU,16]
                       const float* __restrict__ bn,    // [NB,8]
                       const float* __restrict__ bg,    // [NB,32]
                       const float* __restrict__ Wu,    // [16,64]
                       const float* __restrict__ bu,    // [64]
                       const float* __restrict__ Wn,    // [8,64]
                       const float* __restrict__ bnb,   // [64]
                       const float* __restrict__ Wg,    // [32,64]
                       const float* __restrict__ bgb,   // [64]
                       const float* __restrict__ dis,
                       float* __restrict__ out0, bf16* __restrict__ y0,
                       int N, int NU) {
    int tid = threadIdx.x;
    int lane = tid & 63;
    int node = blockIdx.x * 4 + (tid >> 6);
    if (node >= N) return;

    float p;
    if (node < NU) {
        p = bu[lane];
        const float* f = uf + (size_t)node * 16;
        #pragma unroll
        for (int k = 0; k < 16; k++)
            p += f[k] * Wu[k * D + lane];
    } else {
        int b = node - NU;
        p = bnb[lane] + bgb[lane];
        const float* fn = bn + (size_t)b * 8;
        #pragma unroll
        for (int k = 0; k < 8; k++)
            p += fn[k] * Wn[k * D + lane];
        const float* fg = bg + (size_t)b * 32;
        #pragma unroll
        for (int k = 0; k < 32; k++)
            p += fg[k] * Wg[k * D + lane];
    }

    size_t idx = (size_t)node * D + lane;
    float v = emb[idx] + p;
    out0[idx] = v;
    y0[idx]   = __float2bfloat16(dis[node] * v);
}

// ---------------- propagation layer: pure row-sum gather, masked unroll-8 ----------------
// y_in is pre-scaled by dis[src]. x = dis[t] * sum; y_out = bf16(dis[t] * x).

__global__ __launch_bounds__(256) void k_prop(const int* __restrict__ row_end,
                       const int* __restrict__ csr,
                       const float* __restrict__ dis,
                       const bf16* __restrict__ y_in,
                       bf16* __restrict__ x_out,
                       bf16* __restrict__ y_out, int N, int E) {
    int lane = threadIdx.x & 63;
    int node = blockIdx.x * 4 + (threadIdx.x >> 6);
    if (node >= N) return;

    int s = (node > 0) ? row_end[node - 1] : 0;
    int e = row_end[node];

    float a[8] = {0, 0, 0, 0, 0, 0, 0, 0};
    for (int i = s; i < e; i += 8) {
        #pragma unroll
        for (int u = 0; u < 8; u++) {
            int idx = i + u;
            int j = csr[min(idx, E - 1)];
            float v = __bfloat162float(y_in[(size_t)j * D + lane]);
            a[u] += (idx < e) ? v : 0.0f;
        }
    }
    float sum = ((a[0] + a[1]) + (a[2] + a[3])) + ((a[4] + a[5]) + (a[6] + a[7]));

    float dt = dis[node];
    float x  = dt * sum;
    size_t o = (size_t)node * D + lane;
    x_out[o] = __float2bfloat16(x);
    y_out[o] = __float2bfloat16(dt * x);
}

// ---------------- last layer fused with final mean: out1 = (e0 + x1 + x2 + x3)/4 ----------------

__global__ __launch_bounds__(256) void k_prop_last(const int* __restrict__ row_end,
                       const int* __restrict__ csr,
                       const float* __restrict__ dis,
                       const bf16* __restrict__ y_in,
                       const float* __restrict__ out0,
                       const bf16* __restrict__ x1,
                       const bf16* __restrict__ x2,
                       float* __restrict__ out1, int N, int E) {
    int lane = threadIdx.x & 63;
    int node = blockIdx.x * 4 + (threadIdx.x >> 6);
    if (node >= N) return;

    int s = (node > 0) ? row_end[node - 1] : 0;
    int e = row_end[node];

    float a[8] = {0, 0, 0, 0, 0, 0, 0, 0};
    for (int i = s; i < e; i += 8) {
        #pragma unroll
        for (int u = 0; u < 8; u++) {
            int idx = i + u;
            int j = csr[min(idx, E - 1)];
            float v = __bfloat162float(y_in[(size_t)j * D + lane]);
            a[u] += (idx < e) ? v : 0.0f;
        }
    }
    float sum = ((a[0] + a[1]) + (a[2] + a[3])) + ((a[4] + a[5]) + (a[6] + a[7]));

    float x3 = dis[node] * sum;
    size_t o = (size_t)node * D + lane;
    out1[o] = (out0[o] + __bfloat162float(x1[o]) + __bfloat162float(x2[o]) + x3) * 0.25f;
}

// ---------------- launch ----------------

extern "C" void kernel_launch(void* const* d_in, const int* in_sizes, int n_in,
                              void* d_out, int out_size, void* d_ws, size_t ws_size,
                              hipStream_t stream) {
    const int E  = in_sizes[0] / 2;
    const int N  = in_sizes[1] / D;
    const int NU = in_sizes[2] / 16;

    const int*   frm = (const int*)d_in[0];
    const int*   to  = frm + E;
    const float* emb = (const float*)d_in[1];
    const float* uf  = (const float*)d_in[2];
    const float* bn  = (const float*)d_in[3];
    const float* bg  = (const float*)d_in[4];
    const float* Wu  = (const float*)d_in[5];
    const float* bu  = (const float*)d_in[6];
    const float* Wn  = (const float*)d_in[7];
    const float* bnb = (const float*)d_in[8];
    const float* Wg  = (const float*)d_in[9];
    const float* bgb = (const float*)d_in[10];

    // workspace layout
    char* p = (char*)d_ws;
    const size_t ND = (size_t)N * D;
    bf16*  y0        = (bf16*)p;   p += ND * sizeof(bf16);
    bf16*  y1        = (bf16*)p;   p += ND * sizeof(bf16);
    bf16*  y2        = (bf16*)p;   p += ND * sizeof(bf16);
    bf16*  x1        = (bf16*)p;   p += ND * sizeof(bf16);
    bf16*  x2        = (bf16*)p;   p += ND * sizeof(bf16);
    float* dis       = (float*)p;  p += (size_t)N * sizeof(float);
    int*   deg       = (int*)p;    p += (size_t)N * sizeof(int);
    int*   row_start = (int*)p;    p += ((size_t)N + 16) * sizeof(int);
    int*   block_sums= (int*)p;    p += 1024 * sizeof(int);
    int*   csr       = (int*)p;    p += (size_t)E * sizeof(int);

    hipMemsetAsync(deg, 0, (size_t)N * sizeof(int), stream);

    const int TB = 256;
    const int gridE4 = (E + TB * 4 - 1) / (TB * 4);   // 4 edges per thread
    const int gridN  = (N + TB - 1) / TB;
    const int nb     = gridN;                 // scan blocks (must be <= 1024)
    const int gridNode = (N + 3) / 4;         // 4 nodes (waves) per 256-thread block

    k_deg  <<<gridE4, TB, 0, stream>>>(to, deg, E);
    k_scan1<<<nb,     TB, 0, stream>>>(deg, dis, row_start, block_sums, N);
    k_scan2<<<1,    1024, 0, stream>>>(block_sums, nb);
    k_scan3<<<gridN,  TB, 0, stream>>>(row_start, block_sums, N);
    k_fill <<<gridE4, TB, 0, stream>>>(frm, to, row_start, csr, E);

    float* out0 = (float*)d_out;       // emb0 output (fp32)
    float* out1 = out0 + ND;           // layer-mean output (fp32)

    k_emb0<<<gridNode, TB, 0, stream>>>(emb, uf, bn, bg, Wu, bu, Wn, bnb, Wg, bgb,
                                        dis, out0, y0, N, NU);

    // row_start now holds row-END offsets (mutated by k_fill)
    k_prop     <<<gridNode, TB, 0, stream>>>(row_start, csr, dis, y0, x1, y1, N, E);
    k_prop     <<<gridNode, TB, 0, stream>>>(row_start, csr, dis, y1, x2, y2, N, E);
    k_prop_last<<<gridNode, TB, 0, stream>>>(row_start, csr, dis, y2, out0, x1, x2, out1, N, E);
}

// Round 6
// 574.746 us; speedup vs baseline: 2.0392x; 1.1530x over previous
//
#include <hip/hip_runtime.h>
#include <hip/hip_bf16.h>

typedef __hip_bfloat16 bf16;

#define D 64        // LATENT
#define BSH 8       // 256 nodes per bucket
#define CAP 5120    // bucket capacity (mean 4096, sigma ~64 -> 16 sigma margin)
#define EPB 4096    // edges per k_part block

// ---------------- init bucket cursors + row_start sentinel ----------------

__global__ __launch_bounds__(256) void k_initcur(int* __restrict__ gcur, int nbk,
                                                 int* __restrict__ row_start, int N, int E) {
    int i = blockIdx.x * 256 + threadIdx.x;
    if (i < nbk) gcur[i] = i * CAP;
    if (i == 0) row_start[N] = E;
}

// ---------------- degree (4 independent atomic chains per thread) ----------------

__global__ __launch_bounds__(256) void k_deg(const int* __restrict__ to,
                                             int* __restrict__ deg, int E) {
    int t0 = blockIdx.x * blockDim.x + threadIdx.x;
    int stride = gridDim.x * blockDim.x;
    #pragma unroll
    for (int u = 0; u < 4; u++) {
        int i = t0 + u * stride;
        if (i < E) atomicAdd(&deg[to[i]], 1);
    }
}

// ---------------- scan1: block-local exclusive scan + dis = deg^-1/2 ----------------

__global__ void k_scan1(const int* __restrict__ deg, float* __restrict__ dis,
                        int* __restrict__ row_start, int* __restrict__ block_sums, int N) {
    __shared__ int s[256];
    int t = threadIdx.x;
    int i = blockIdx.x * 256 + t;
    int x = (i < N) ? deg[i] : 0;
    if (i < N) dis[i] = (x > 0) ? rsqrtf((float)x) : 0.0f;
    s[t] = x;
    __syncthreads();
    #pragma unroll
    for (int off = 1; off < 256; off <<= 1) {
        int v = s[t] + ((t >= off) ? s[t - off] : 0);
        __syncthreads();
        s[t] = v;
        __syncthreads();
    }
    if (i < N) row_start[i] = s[t] - x;          // exclusive within block
    if (t == 255) block_sums[blockIdx.x] = s[255];
}

__global__ void k_scan2(int* __restrict__ bs, int nb) {
    __shared__ int s[1024];
    int t = threadIdx.x;
    int x = (t < nb) ? bs[t] : 0;
    s[t] = x;
    __syncthreads();
    #pragma unroll
    for (int off = 1; off < 1024; off <<= 1) {
        int v = s[t] + ((t >= off) ? s[t - off] : 0);
        __syncthreads();
        s[t] = v;
        __syncthreads();
    }
    if (t < nb) bs[t] = s[t] - x;                // exclusive block offsets
}

__global__ void k_scan3(int* __restrict__ row_start, const int* __restrict__ bs, int N) {
    int i = blockIdx.x * 256 + threadIdx.x;
    if (i < N) row_start[i] += bs[i >> 8];
}

// ---------------- pass 1: partition edges into target buckets ----------------
// record = (frm << 8) | (to & 255); bucket = to >> 8, fixed CAP region per bucket.

__global__ __launch_bounds__(256) void k_part(const int* __restrict__ frm,
                                              const int* __restrict__ to,
                                              int* __restrict__ gcur,
                                              int* __restrict__ be, int E, int nbk) {
    __shared__ int h[1024];
    int tid = threadIdx.x;
    for (int i = tid; i < 1024; i += 256) h[i] = 0;
    __syncthreads();

    int base = blockIdx.x * EPB;
    int  f[16], bk[16], tl[16];
    bool va[16];
    #pragma unroll
    for (int k = 0; k < 16; k++) {
        int i = base + k * 256 + tid;
        va[k] = (i < E);
        int ic = va[k] ? i : 0;
        int t = to[ic];
        f[k]  = frm[ic];
        bk[k] = t >> BSH;
        tl[k] = t & 255;
        if (va[k]) atomicAdd(&h[bk[k]], 1);
    }
    __syncthreads();
    // reserve contiguous space in each bucket's region; h[b] becomes running cursor
    for (int b = tid; b < nbk; b += 256) {
        int c = h[b];
        h[b] = (c > 0) ? atomicAdd(&gcur[b], c) : 0;
    }
    __syncthreads();
    #pragma unroll
    for (int k = 0; k < 16; k++) {
        if (va[k]) {
            int pos = atomicAdd(&h[bk[k]], 1);
            be[pos] = (f[k] << 8) | tl[k];
        }
    }
}

// ---------------- pass 2: per-bucket scatter into CSR (LDS cursors, L2-local writes) ----

__global__ __launch_bounds__(256) void k_scatter(const int* __restrict__ gcur,
                                                 const int* __restrict__ be,
                                                 const int* __restrict__ row_start,
                                                 int* __restrict__ csr, int N) {
    __shared__ int cur[256];
    int b = blockIdx.x;
    int t = threadIdx.x;
    int node = (b << BSH) + t;
    cur[t] = (node < N) ? row_start[node] : 0;
    __syncthreads();

    int base = b * CAP;
    int cnt  = gcur[b] - base;
    for (int i = t; i < cnt; i += 256) {
        int rec = be[base + i];
        int pos = atomicAdd(&cur[rec & 255], 1);
        csr[pos] = rec >> 8;
    }
}

// ---------------- emb0 = embedding + feature projection ----------------
// One wave per node; lane = dim. out0 = fp32 emb0; y0 = bf16(dis * emb0) gather table.

__global__ __launch_bounds__(256) void k_emb0(const float* __restrict__ emb,
                       const float* __restrict__ uf,    // [NU,16]
                       const float* __restrict__ bn,    // [NB,8]
                       const float* __restrict__ bg,    // [NB,32]
                       const float* __restrict__ Wu,    // [16,64]
                       const float* __restrict__ bu,    // [64]
                       const float* __restrict__ Wn,    // [8,64]
                       const float* __restrict__ bnb,   // [64]
                       const float* __restrict__ Wg,    // [32,64]
                       const float* __restrict__ bgb,   // [64]
                       const float* __restrict__ dis,
                       float* __restrict__ out0, bf16* __restrict__ y0,
                       int N, int NU) {
    int tid = threadIdx.x;
    int lane = tid & 63;
    int node = blockIdx.x * 4 + (tid >> 6);
    if (node >= N) return;

    float p;
    if (node < NU) {
        p = bu[lane];
        const float* f = uf + (size_t)node * 16;
        #pragma unroll
        for (int k = 0; k < 16; k++)
            p += f[k] * Wu[k * D + lane];
    } else {
        int b = node - NU;
        p = bnb[lane] + bgb[lane];
        const float* fn = bn + (size_t)b * 8;
        #pragma unroll
        for (int k = 0; k < 8; k++)
            p += fn[k] * Wn[k * D + lane];
        const float* fg = bg + (size_t)b * 32;
        #pragma unroll
        for (int k = 0; k < 32; k++)
            p += fg[k] * Wg[k * D + lane];
    }

    size_t idx = (size_t)node * D + lane;
    float v = emb[idx] + p;
    out0[idx] = v;
    y0[idx]   = __float2bfloat16(dis[node] * v);
}

// ---------------- propagation layer: pure row-sum gather, masked unroll-8 ----------------
// y_in is pre-scaled by dis[src]. x = dis[t] * sum; y_out = bf16(dis[t] * x).
// Masked lanes re-read the row's LAST edge (line already in flight), not a random one.

__global__ __launch_bounds__(256) void k_prop(const int* __restrict__ row_start,
                       const int* __restrict__ csr,
                       const float* __restrict__ dis,
                       const bf16* __restrict__ y_in,
                       bf16* __restrict__ x_out,
                       bf16* __restrict__ y_out, int N) {
    int lane = threadIdx.x & 63;
    int node = blockIdx.x * 4 + (threadIdx.x >> 6);
    if (node >= N) return;

    int s = row_start[node];
    int e = row_start[node + 1];

    float a[8] = {0, 0, 0, 0, 0, 0, 0, 0};
    for (int i = s; i < e; i += 8) {
        #pragma unroll
        for (int u = 0; u < 8; u++) {
            int idx = i + u;
            int j = csr[min(idx, e - 1)];
            float v = __bfloat162float(y_in[(size_t)j * D + lane]);
            a[u] += (idx < e) ? v : 0.0f;
        }
    }
    float sum = ((a[0] + a[1]) + (a[2] + a[3])) + ((a[4] + a[5]) + (a[6] + a[7]));

    float dt = dis[node];
    float x  = dt * sum;
    size_t o = (size_t)node * D + lane;
    x_out[o] = __float2bfloat16(x);
    y_out[o] = __float2bfloat16(dt * x);
}

// ---------------- last layer fused with final mean: out1 = (e0 + x1 + x2 + x3)/4 ----------------

__global__ __launch_bounds__(256) void k_prop_last(const int* __restrict__ row_start,
                       const int* __restrict__ csr,
                       const float* __restrict__ dis,
                       const bf16* __restrict__ y_in,
                       const float* __restrict__ out0,
                       const bf16* __restrict__ x1,
                       const bf16* __restrict__ x2,
                       float* __restrict__ out1, int N) {
    int lane = threadIdx.x & 63;
    int node = blockIdx.x * 4 + (threadIdx.x >> 6);
    if (node >= N) return;

    int s = row_start[node];
    int e = row_start[node + 1];

    float a[8] = {0, 0, 0, 0, 0, 0, 0, 0};
    for (int i = s; i < e; i += 8) {
        #pragma unroll
        for (int u = 0; u < 8; u++) {
            int idx = i + u;
            int j = csr[min(idx, e - 1)];
            float v = __bfloat162float(y_in[(size_t)j * D + lane]);
            a[u] += (idx < e) ? v : 0.0f;
        }
    }
    float sum = ((a[0] + a[1]) + (a[2] + a[3])) + ((a[4] + a[5]) + (a[6] + a[7]));

    float x3 = dis[node] * sum;
    size_t o = (size_t)node * D + lane;
    out1[o] = (out0[o] + __bfloat162float(x1[o]) + __bfloat162float(x2[o]) + x3) * 0.25f;
}

// ---------------- launch ----------------

extern "C" void kernel_launch(void* const* d_in, const int* in_sizes, int n_in,
                              void* d_out, int out_size, void* d_ws, size_t ws_size,
                              hipStream_t stream) {
    const int E  = in_sizes[0] / 2;
    const int N  = in_sizes[1] / D;
    const int NU = in_sizes[2] / 16;
    const int nbk = (N + 255) >> BSH;        // buckets of 256 nodes

    const int*   frm = (const int*)d_in[0];
    const int*   to  = frm + E;
    const float* emb = (const float*)d_in[1];
    const float* uf  = (const float*)d_in[2];
    const float* bn  = (const float*)d_in[3];
    const float* bg  = (const float*)d_in[4];
    const float* Wu  = (const float*)d_in[5];
    const float* bu  = (const float*)d_in[6];
    const float* Wn  = (const float*)d_in[7];
    const float* bnb = (const float*)d_in[8];
    const float* Wg  = (const float*)d_in[9];
    const float* bgb = (const float*)d_in[10];

    // workspace layout
    char* p = (char*)d_ws;
    const size_t ND = (size_t)N * D;
    bf16*  y0        = (bf16*)p;   p += ND * sizeof(bf16);    // also reused as y2
    bf16*  y1        = (bf16*)p;   p += ND * sizeof(bf16);
    bf16*  x1        = (bf16*)p;   p += ND * sizeof(bf16);
    bf16*  x2        = (bf16*)p;   p += ND * sizeof(bf16);
    float* dis       = (float*)p;  p += (size_t)N * sizeof(float);
    int*   deg       = (int*)p;    p += (size_t)N * sizeof(int);
    int*   row_start = (int*)p;    p += ((size_t)N + 16) * sizeof(int);
    int*   block_sums= (int*)p;    p += 1024 * sizeof(int);
    int*   gcur      = (int*)p;    p += (size_t)nbk * sizeof(int);
    int*   csr       = (int*)p;    p += (size_t)E * sizeof(int);
    int*   be        = (int*)p;    p += (size_t)nbk * CAP * sizeof(int);

    hipMemsetAsync(deg, 0, (size_t)N * sizeof(int), stream);

    const int TB = 256;
    const int gridE4 = (E + TB * 4 - 1) / (TB * 4);   // 4 edges per thread (deg)
    const int gridN  = (N + TB - 1) / TB;
    const int nb     = gridN;                 // scan blocks (must be <= 1024)
    const int gridNode = (N + 3) / 4;         // 4 nodes (waves) per 256-thread block
    const int gridPart = (E + EPB - 1) / EPB;

    k_initcur<<<(nbk + TB - 1) / TB, TB, 0, stream>>>(gcur, nbk, row_start, N, E);
    k_deg    <<<gridE4, TB, 0, stream>>>(to, deg, E);
    k_scan1  <<<nb,     TB, 0, stream>>>(deg, dis, row_start, block_sums, N);
    k_scan2  <<<1,    1024, 0, stream>>>(block_sums, nb);
    k_scan3  <<<gridN,  TB, 0, stream>>>(row_start, block_sums, N);
    k_part   <<<gridPart, TB, 0, stream>>>(frm, to, gcur, be, E, nbk);
    k_scatter<<<nbk,    TB, 0, stream>>>(gcur, be, row_start, csr, N);

    float* out0 = (float*)d_out;       // emb0 output (fp32)
    float* out1 = out0 + ND;           // layer-mean output (fp32)

    k_emb0<<<gridNode, TB, 0, stream>>>(emb, uf, bn, bg, Wu, bu, Wn, bnb, Wg, bgb,
                                        dis, out0, y0, N, NU);

    k_prop     <<<gridNode, TB, 0, stream>>>(row_start, csr, dis, y0, x1, y1, N);
    k_prop     <<<gridNode, TB, 0, stream>>>(row_start, csr, dis, y1, x2, y0, N);  // y2 -> y0
    k_prop_last<<<gridNode, TB, 0, stream>>>(row_start, csr, dis, y0, out0, x1, x2, out1, N);
}

// Round 7
// 478.648 us; speedup vs baseline: 2.4486x; 1.2008x over previous
//
#include <hip/hip_runtime.h>
#include <hip/hip_bf16.h>

typedef __hip_bfloat16 bf16;

#define D 64        // LATENT
#define BSH 8       // 256 nodes per bucket
#define CAP 5120    // bucket capacity (mean 4096, sigma ~64 -> 16 sigma margin)
#define EPB 4096    // edges per k_part block

// ---------------- init bucket cursors ----------------

__global__ __launch_bounds__(256) void k_initcur(int* __restrict__ gcur, int nbk) {
    int i = blockIdx.x * 256 + threadIdx.x;
    if (i < nbk) gcur[i] = i * CAP;
}

// ---------------- pass 1: partition edges into target buckets ----------------
// record = (frm << 8) | (to & 255); bucket = to >> 8, fixed CAP region per bucket.

__global__ __launch_bounds__(256) void k_part(const int* __restrict__ frm,
                                              const int* __restrict__ to,
                                              int* __restrict__ gcur,
                                              int* __restrict__ be, int E, int nbk) {
    __shared__ int h[1024];
    int tid = threadIdx.x;
    for (int i = tid; i < 1024; i += 256) h[i] = 0;
    __syncthreads();

    int base = blockIdx.x * EPB;
    int  f[16], bk[16], tl[16];
    bool va[16];
    #pragma unroll
    for (int k = 0; k < 16; k++) {
        int i = base + k * 256 + tid;
        va[k] = (i < E);
        int ic = va[k] ? i : 0;
        int t = to[ic];
        f[k]  = frm[ic];
        bk[k] = t >> BSH;
        tl[k] = t & 255;
        if (va[k]) atomicAdd(&h[bk[k]], 1);
    }
    __syncthreads();
    // reserve contiguous space in each bucket's region; h[b] becomes running cursor
    for (int b = tid; b < nbk; b += 256) {
        int c = h[b];
        h[b] = (c > 0) ? atomicAdd(&gcur[b], c) : 0;
    }
    __syncthreads();
    #pragma unroll
    for (int k = 0; k < 16; k++) {
        if (va[k]) {
            int pos = atomicAdd(&h[bk[k]], 1);
            be[pos] = (f[k] << 8) | tl[k];
        }
    }
}

// ---------------- scan bucket counts -> bstart; single block ----------------

__global__ void k_bscan(const int* __restrict__ gcur, int* __restrict__ bstart,
                        int* __restrict__ row_start, int nbk, int N, int E) {
    __shared__ int s[1024];
    int t = threadIdx.x;
    int x = (t < nbk) ? (gcur[t] - t * CAP) : 0;   // bucket count
    s[t] = x;
    __syncthreads();
    #pragma unroll
    for (int off = 1; off < 1024; off <<= 1) {
        int v = s[t] + ((t >= off) ? s[t - off] : 0);
        __syncthreads();
        s[t] = v;
        __syncthreads();
    }
    if (t < nbk) bstart[t] = s[t] - x;             // exclusive
    if (t == 0) row_start[N] = E;
}

// ---------------- pass 2: per-bucket hist + scan + scatter (all LDS atomics) ------
// Computes deg/dis/row_start for the bucket's 256 nodes, then scatters into CSR.

__global__ __launch_bounds__(256) void k_scatter(const int* __restrict__ gcur,
                                                 const int* __restrict__ bstart,
                                                 const int* __restrict__ be,
                                                 int* __restrict__ row_start,
                                                 float* __restrict__ dis,
                                                 int* __restrict__ csr, int N) {
    __shared__ int hist[256];
    __shared__ int scn[256];
    int b = blockIdx.x;
    int t = threadIdx.x;
    hist[t] = 0;
    __syncthreads();

    int base = b * CAP;
    int cnt  = gcur[b] - base;
    for (int i = t; i < cnt; i += 256)
        atomicAdd(&hist[be[base + i] & 255], 1);
    __syncthreads();

    int d = hist[t];
    // exclusive scan of hist
    scn[t] = d;
    __syncthreads();
    #pragma unroll
    for (int off = 1; off < 256; off <<= 1) {
        int v = scn[t] + ((t >= off) ? scn[t - off] : 0);
        __syncthreads();
        scn[t] = v;
        __syncthreads();
    }
    int rs = bstart[b] + (scn[t] - d);

    int node = (b << BSH) + t;
    if (node < N) {
        row_start[node] = rs;
        dis[node] = (d > 0) ? rsqrtf((float)d) : 0.0f;
    }
    hist[t] = rs;                                   // becomes cursor
    __syncthreads();

    for (int i = t; i < cnt; i += 256) {
        int rec = be[base + i];
        int pos = atomicAdd(&hist[rec & 255], 1);
        csr[pos] = rec >> 8;
    }
}

// ---------------- emb0 = embedding + feature projection ----------------
// One wave per node; lane = dim. out0 = fp32 emb0; y0 = bf16(dis * emb0) gather table.

__global__ __launch_bounds__(256) void k_emb0(const float* __restrict__ emb,
                       const float* __restrict__ uf,    // [NU,16]
                       const float* __restrict__ bn,    // [NB,8]
                       const float* __restrict__ bg,    // [NB,32]
                       const float* __restrict__ Wu,    // [16,64]
                       const float* __restrict__ bu,    // [64]
                       const float* __restrict__ Wn,    // [8,64]
                       const float* __restrict__ bnb,   // [64]
                       const float* __restrict__ Wg,    // [32,64]
                       const float* __restrict__ bgb,   // [64]
                       const float* __restrict__ dis,
                       float* __restrict__ out0, bf16* __restrict__ y0,
                       int N, int NU) {
    int tid = threadIdx.x;
    int lane = tid & 63;
    int node = blockIdx.x * 4 + (tid >> 6);
    if (node >= N) return;

    float p;
    if (node < NU) {
        p = bu[lane];
        const float* f = uf + (size_t)node * 16;
        #pragma unroll
        for (int k = 0; k < 16; k++)
            p += f[k] * Wu[k * D + lane];
    } else {
        int b = node - NU;
        p = bnb[lane] + bgb[lane];
        const float* fn = bn + (size_t)b * 8;
        #pragma unroll
        for (int k = 0; k < 8; k++)
            p += fn[k] * Wn[k * D + lane];
        const float* fg = bg + (size_t)b * 32;
        #pragma unroll
        for (int k = 0; k < 32; k++)
            p += fg[k] * Wg[k * D + lane];
    }

    size_t idx = (size_t)node * D + lane;
    float v = emb[idx] + p;
    out0[idx] = v;
    y0[idx]   = __float2bfloat16(dis[node] * v);
}

// ---------------- propagation layer: pure row-sum gather, masked unroll-8 ----------------
// y_in is pre-scaled by dis[src]. x = dis[t] * sum; y_out = bf16(dis[t] * x).
// Masked lanes re-read the row's LAST edge (line already in flight), not a random one.

__global__ __launch_bounds__(256) void k_prop(const int* __restrict__ row_start,
                       const int* __restrict__ csr,
                       const float* __restrict__ dis,
                       const bf16* __restrict__ y_in,
                       bf16* __restrict__ x_out,
                       bf16* __restrict__ y_out, int N) {
    int lane = threadIdx.x & 63;
    int node = blockIdx.x * 4 + (threadIdx.x >> 6);
    if (node >= N) return;

    int s = row_start[node];
    int e = row_start[node + 1];

    float a[8] = {0, 0, 0, 0, 0, 0, 0, 0};
    for (int i = s; i < e; i += 8) {
        #pragma unroll
        for (int u = 0; u < 8; u++) {
            int idx = i + u;
            int j = csr[min(idx, e - 1)];
            float v = __bfloat162float(y_in[(size_t)j * D + lane]);
            a[u] += (idx < e) ? v : 0.0f;
        }
    }
    float sum = ((a[0] + a[1]) + (a[2] + a[3])) + ((a[4] + a[5]) + (a[6] + a[7]));

    float dt = dis[node];
    float x  = dt * sum;
    size_t o = (size_t)node * D + lane;
    x_out[o] = __float2bfloat16(x);
    y_out[o] = __float2bfloat16(dt * x);
}

// ---------------- last layer fused with final mean: out1 = (e0 + x1 + x2 + x3)/4 ----------------

__global__ __launch_bounds__(256) void k_prop_last(const int* __restrict__ row_start,
                       const int* __restrict__ csr,
                       const float* __restrict__ dis,
                       const bf16* __restrict__ y_in,
                       const float* __restrict__ out0,
                       const bf16* __restrict__ x1,
                       const bf16* __restrict__ x2,
                       float* __restrict__ out1, int N) {
    int lane = threadIdx.x & 63;
    int node = blockIdx.x * 4 + (threadIdx.x >> 6);
    if (node >= N) return;

    int s = row_start[node];
    int e = row_start[node + 1];

    float a[8] = {0, 0, 0, 0, 0, 0, 0, 0};
    for (int i = s; i < e; i += 8) {
        #pragma unroll
        for (int u = 0; u < 8; u++) {
            int idx = i + u;
            int j = csr[min(idx, e - 1)];
            float v = __bfloat162float(y_in[(size_t)j * D + lane]);
            a[u] += (idx < e) ? v : 0.0f;
        }
    }
    float sum = ((a[0] + a[1]) + (a[2] + a[3])) + ((a[4] + a[5]) + (a[6] + a[7]));

    float x3 = dis[node] * sum;
    size_t o = (size_t)node * D + lane;
    out1[o] = (out0[o] + __bfloat162float(x1[o]) + __bfloat162float(x2[o]) + x3) * 0.25f;
}

// ---------------- launch ----------------

extern "C" void kernel_launch(void* const* d_in, const int* in_sizes, int n_in,
                              void* d_out, int out_size, void* d_ws, size_t ws_size,
                              hipStream_t stream) {
    const int E  = in_sizes[0] / 2;
    const int N  = in_sizes[1] / D;
    const int NU = in_sizes[2] / 16;
    const int nbk = (N + 255) >> BSH;        // buckets of 256 nodes (<= 1024 required)

    const int*   frm = (const int*)d_in[0];
    const int*   to  = frm + E;
    const float* emb = (const float*)d_in[1];
    const float* uf  = (const float*)d_in[2];
    const float* bn  = (const float*)d_in[3];
    const float* bg  = (const float*)d_in[4];
    const float* Wu  = (const float*)d_in[5];
    const float* bu  = (const float*)d_in[6];
    const float* Wn  = (const float*)d_in[7];
    const float* bnb = (const float*)d_in[8];
    const float* Wg  = (const float*)d_in[9];
    const float* bgb = (const float*)d_in[10];

    // workspace layout
    char* p = (char*)d_ws;
    const size_t ND = (size_t)N * D;
    bf16*  y0        = (bf16*)p;   p += ND * sizeof(bf16);    // also reused as y2
    bf16*  y1        = (bf16*)p;   p += ND * sizeof(bf16);
    bf16*  x1        = (bf16*)p;   p += ND * sizeof(bf16);
    bf16*  x2        = (bf16*)p;   p += ND * sizeof(bf16);
    float* dis       = (float*)p;  p += (size_t)N * sizeof(float);
    int*   row_start = (int*)p;    p += ((size_t)N + 16) * sizeof(int);
    int*   bstart    = (int*)p;    p += 1024 * sizeof(int);
    int*   gcur      = (int*)p;    p += (size_t)nbk * sizeof(int);
    int*   csr       = (int*)p;    p += (size_t)E * sizeof(int);
    int*   be        = (int*)p;    p += (size_t)nbk * CAP * sizeof(int);

    const int TB = 256;
    const int gridNode = (N + 3) / 4;         // 4 nodes (waves) per 256-thread block
    const int gridPart = (E + EPB - 1) / EPB;

    k_initcur<<<(nbk + TB - 1) / TB, TB, 0, stream>>>(gcur, nbk);
    k_part   <<<gridPart, TB, 0, stream>>>(frm, to, gcur, be, E, nbk);
    k_bscan  <<<1, 1024, 0, stream>>>(gcur, bstart, row_start, nbk, N, E);
    k_scatter<<<nbk, TB, 0, stream>>>(gcur, bstart, be, row_start, dis, csr, N);

    float* out0 = (float*)d_out;       // emb0 output (fp32)
    float* out1 = out0 + ND;           // layer-mean output (fp32)

    k_emb0<<<gridNode, TB, 0, stream>>>(emb, uf, bn, bg, Wu, bu, Wn, bnb, Wg, bgb,
                                        dis, out0, y0, N, NU);

    k_prop     <<<gridNode, TB, 0, stream>>>(row_start, csr, dis, y0, x1, y1, N);
    k_prop     <<<gridNode, TB, 0, stream>>>(row_start, csr, dis, y1, x2, y0, N);  // y2 -> y0
    k_prop_last<<<gridNode, TB, 0, stream>>>(row_start, csr, dis, y0, out0, x1, x2, out1, N);
}